// Round 10
// baseline (334.651 us; speedup 1.0000x reference)
//
#include <hip/hip_runtime.h>

#define TOK  10560
#define CIMG 3072
#define KHD  1024

typedef unsigned short ushort_t;
typedef unsigned int u32;
using bf16x8 = __attribute__((ext_vector_type(8))) __bf16;
using f32x4  = __attribute__((ext_vector_type(4))) float;

#define GLD_LDS16(gp, lp) __builtin_amdgcn_global_load_lds( \
    (const __attribute__((address_space(1))) u32*)(gp), \
    (__attribute__((address_space(3))) u32*)(lp), 16, 0, 0)

static __device__ __forceinline__ unsigned short f2bf(float f){
  union { float f; unsigned u; } x; x.f = f;
  unsigned r = x.u + 0x7fffu + ((x.u >> 16) & 1u);
  return (unsigned short)(r >> 16);
}
static __device__ __forceinline__ float bf2f(unsigned short u){
  union { unsigned u; float f; } x; x.u = ((unsigned)u) << 16; return x.f;
}
static __device__ __forceinline__ float wave_sum(float v){
  #pragma unroll
  for (int off = 32; off > 0; off >>= 1) v += __shfl_xor(v, off, 64);
  return v;
}

// ---------------- conditioning MLP layer 1: h1 = silu(cp@w1+b1) --------------
__global__ __launch_bounds__(256) void k_pre1(const float* __restrict__ cond,
    const float* __restrict__ w1, const float* __restrict__ b1,
    float* __restrict__ h1){
  __shared__ float cs[16][16];
  int t = threadIdx.x;
  if (t < 256) cs[t >> 4][t & 15] = cond[(64 + (t >> 4)) * 16 + (t & 15)];
  __syncthreads();
  #pragma unroll
  for (int i = 0; i < 4; ++i){
    int idx = blockIdx.x * 256 + t + i * 2048;
    int r = idx >> 9, c = idx & 511;
    float s = b1[c];
    #pragma unroll
    for (int j = 0; j < 16; ++j) s += cs[r][j] * w1[j * 512 + c];
    h1[idx] = s / (1.f + __expf(-s));   // silu
  }
}

// ---------------- conditioning MLP layer 2: emb = h1@w2 + b2 -----------------
__global__ __launch_bounds__(256) void k_pre2(const float* __restrict__ h1,
    const float* __restrict__ w2, const float* __restrict__ b2,
    float* __restrict__ emb){
  int idx = blockIdx.x * 256 + threadIdx.x;
  int r = idx >> 9, c = idx & 511;
  const float* hp = h1 + r * 512;
  const float* wp = w2 + c;
  float acc = b2[c];
  #pragma unroll 8
  for (int j = 0; j < 512; ++j) acc += hp[j] * wp[(size_t)j * 512];
  emb[idx] = acc;
}

// ---------------- kv = mf @ kv_w, split-K partials (deterministic) ----------
__global__ __launch_bounds__(256) void k_kv(const float* __restrict__ emb,
                                            const float* __restrict__ kvw,
                                            float* __restrict__ part){
  int bl = blockIdx.x;                 // 3 l * 8 ntile * 16 kchunk = 384
  int l = bl / 128, rem = bl % 128, nt = rem / 16, kc = rem % 16;
  int n = nt * 256 + threadIdx.x;
  const float* e = emb + 2048 * l + kc * 256;   // mf[l][r] = emb[2048l + r]
  const float* w = kvw + (size_t)(kc * 256) * 2048 + n;
  float acc = 0.f;
  for (int r = 0; r < 256; ++r) acc += e[r] * w[(size_t)r * 2048];
  part[kc * 6144 + l * 2048 + n] = acc;
}

// ---------------- reduce partials, bias, k-RMSNorm ---------------------------
__global__ void k_knorm(const float* __restrict__ part, const float* __restrict__ kvb,
                        const float* __restrict__ knw, float* __restrict__ kn,
                        float* __restrict__ vv){
  int wid = threadIdx.x >> 6, lane = threadIdx.x & 63;
  for (int i = 0; i < 12; ++i){
    int g = wid * 12 + i;               // 0..47 = (l,h)
    int l = g >> 4, h = g & 15;
    int ik = l * 2048 + h * 64 + lane;
    float kk = kvb[h * 64 + lane];
    float v  = kvb[1024 + h * 64 + lane];
    for (int p = 0; p < 16; ++p){ kk += part[p * 6144 + ik]; v += part[p * 6144 + ik + 1024]; }
    float ss = wave_sum(kk * kk);
    kn[l * 1024 + h * 64 + lane] = kk * rsqrtf(ss * (1.f/64.f) + 1e-6f) * knw[lane];
    vv[l * 1024 + h * 64 + lane] = v;
  }
}

// ---------------- transpose + f32->bf16 weight convert: dst[C][R] ------------
__global__ __launch_bounds__(256) void k_tconv(const float* __restrict__ src,
                                               ushort_t* __restrict__ dst,
                                               int R, int C){
  __shared__ float tile[32][33];
  int nTr = R >> 5;
  int tr = blockIdx.x % nTr, tc = blockIdx.x / nTr;
  int r0 = tr * 32, c0 = tc * 32, t = threadIdx.x;
  #pragma unroll
  for (int i = 0; i < 4; ++i){
    int idx = t + i * 256; int r = idx >> 5, c = idx & 31;
    tile[r][c] = src[(size_t)(r0 + r) * C + c0 + c];
  }
  __syncthreads();
  #pragma unroll
  for (int i = 0; i < 4; ++i){
    int idx = t + i * 256; int rr = idx >> 5, cc = idx & 31;
    dst[(size_t)(c0 + rr) * R + r0 + cc] = f2bf(tile[cc][rr]);
  }
}

// ---------------- x f32 -> bf16 streaming convert ----------------------------
__global__ __launch_bounds__(256) void k_xconv(const float* __restrict__ x,
                                               ushort_t* __restrict__ xb, int n4){
  for (int i = blockIdx.x * 256 + threadIdx.x; i < n4; i += gridDim.x * 256){
    float4 v = ((const float4*)x)[i];
    ushort4 o;
    o.x = f2bf(v.x); o.y = f2bf(v.y); o.z = f2bf(v.z); o.w = f2bf(v.w);
    ((ushort4*)xb)[i] = o;
  }
}

// ======== 256x256 bf16 MFMA Q-GEMM, 8-phase schedule, SPLIT-K=3 ==============
// A bf16 [TOK][3072], Bt bf16 [1024][3072]. Each block: one (mt,nt,ks) ->
// partial over K slice [ks*1024, (ks+1)*1024), written bf16 (no bias) to
// part + ks*TOK*1024. Grid 42*4*3 = 504 -> ~2 full CU rounds (vs 168 = 66%).
// Main loop = round-5/8 passing 8-phase structure with T=16.
__global__ __launch_bounds__(512, 2) void gemm_splitk(
    const ushort_t* __restrict__ A, const ushort_t* __restrict__ Bt,
    ushort_t* __restrict__ part){
  __shared__ __align__(16) unsigned char lds[131072];
  const int tid = threadIdx.x;
  const int lane = tid & 63, wid = tid >> 6;
  const int wm = wid >> 2, wn = wid & 3;     // 2 x 4 waves -> per-wave 128x64
  const int l15 = lane & 15, kg = lane >> 4;

  // XCD swizzle: 504 = 8 * 63 -> bijective
  int bid = blockIdx.x;
  bid = (bid & 7) * 63 + (bid >> 3);
  const int ks = bid % 3;
  const int nt = (bid / 3) & 3;
  const int mt = bid / 12;
  const int mbase = mt << 8, nbase = nt << 8;

  const int sr  = tid >> 1;                       // 0..255
  const int skh = (tid & 1) ^ ((sr >> 2) & 1);    // inverse swizzle on source
  int arow = mbase + sr; if (arow >= TOK) arow = TOK - 1;
  const ushort_t* gA = A  + (size_t)arow * CIMG + ks * 1024 + skh * 8;
  const ushort_t* gB = Bt + (size_t)(nbase + sr) * CIMG + ks * 1024 + skh * 8;
  const int wofs = wid * 1024;

  auto stage = [&](int t, int c, int b){
    const int gk = t * 64 + c * 16;
    unsigned char* dst = lds + b * 65536 + c * 8192 + wofs;
    GLD_LDS16(gA + gk, dst);
    GLD_LDS16(gB + gk, dst + 32768);
  };

  const int arl = wm * 128 + l15;
  const int brl = wn * 64 + l15;
  const int kh  = ((kg & 1) ^ ((l15 >> 2) & 1)) * 16;
  const unsigned aBase = (unsigned)((kg >> 1) * 8192 + arl * 32 + kh);
  const unsigned bBase = (unsigned)(32768 + (kg >> 1) * 8192 + brl * 32 + kh);

  f32x4 acc[8][4];
  #pragma unroll
  for (int m = 0; m < 8; ++m)
    #pragma unroll
    for (int n = 0; n < 4; ++n) acc[m][n] = {0.f, 0.f, 0.f, 0.f};

  bf16x8 afr[4], bfr[4];

#define PH_READ_B(base, KSL) { _Pragma("unroll") \
    for (int n = 0; n < 4; ++n) \
      bfr[n] = *(const bf16x8*)((base) + bBase + (KSL)*16384 + n*512); }
#define PH_READ_A(base, KSL, M0) { _Pragma("unroll") \
    for (int m = 0; m < 4; ++m) \
      afr[m] = *(const bf16x8*)((base) + aBase + (KSL)*16384 + ((M0)+m)*512); }
#define PH_MFMA(R0) { __builtin_amdgcn_s_setprio(1); _Pragma("unroll") \
    for (int m = 0; m < 4; ++m){ _Pragma("unroll") \
      for (int n = 0; n < 4; ++n) \
        acc[(R0)+m][n] = __builtin_amdgcn_mfma_f32_16x16x32_bf16(afr[m], bfr[n], acc[(R0)+m][n], 0, 0, 0); } \
    __builtin_amdgcn_s_setprio(0); }

  const int T = 16;   // 1024 / 64

  stage(0, 0, 0); stage(0, 1, 0); stage(0, 2, 0); stage(0, 3, 0);
  asm volatile("s_waitcnt vmcnt(4)" ::: "memory");
  __builtin_amdgcn_s_barrier();

  for (int t = 0; t < T - 1; ++t){
    const int b = t & 1;
    const unsigned char* base = lds + b * 65536;
    PH_READ_B(base, 0); PH_READ_A(base, 0, 0);
    stage(t + 1, 0, b ^ 1);
    __builtin_amdgcn_s_barrier();
    PH_MFMA(0);
    __builtin_amdgcn_s_barrier();
    PH_READ_A(base, 0, 4);
    stage(t + 1, 1, b ^ 1);
    asm volatile("s_waitcnt vmcnt(4)" ::: "memory");
    __builtin_amdgcn_s_barrier();
    PH_MFMA(4);
    __builtin_amdgcn_s_barrier();
    PH_READ_B(base, 1); PH_READ_A(base, 1, 0);
    stage(t + 1, 2, b ^ 1);
    __builtin_amdgcn_s_barrier();
    PH_MFMA(0);
    __builtin_amdgcn_s_barrier();
    PH_READ_A(base, 1, 4);
    stage(t + 1, 3, b ^ 1);
    asm volatile("s_waitcnt vmcnt(4)" ::: "memory");
    __builtin_amdgcn_s_barrier();
    PH_MFMA(4);
    __builtin_amdgcn_s_barrier();
  }
  {
    const unsigned char* base = lds + ((T - 1) & 1) * 65536;
    PH_READ_B(base, 0); PH_READ_A(base, 0, 0);
    __builtin_amdgcn_s_barrier();
    PH_MFMA(0);
    __builtin_amdgcn_s_barrier();
    PH_READ_A(base, 0, 4);
    asm volatile("s_waitcnt vmcnt(0)" ::: "memory");
    __builtin_amdgcn_s_barrier();
    PH_MFMA(4);
    __builtin_amdgcn_s_barrier();
    PH_READ_B(base, 1); PH_READ_A(base, 1, 0);
    PH_MFMA(0);
    PH_READ_A(base, 1, 4);
    PH_MFMA(4);
  }
#undef PH_READ_B
#undef PH_READ_A
#undef PH_MFMA

  __builtin_amdgcn_s_barrier();

  // bf16 partial out, coalesced via LDS: 2 chunks of 128 rows x 256 cols
  ushort_t* outp = part + (size_t)ks * TOK * KHD;
  ushort_t* cbuf = (ushort_t*)lds;
  for (int c2 = 0; c2 < 2; ++c2){
    if (wm == c2){
      #pragma unroll
      for (int n = 0; n < 4; ++n){
        #pragma unroll
        for (int m = 0; m < 8; ++m){
          #pragma unroll
          for (int j = 0; j < 4; ++j)
            cbuf[(m * 16 + kg * 4 + j) * 256 + wn * 64 + n * 16 + l15] =
                f2bf(acc[m][n][j]);
        }
      }
    }
    __syncthreads();
    #pragma unroll
    for (int it = 0; it < 8; ++it){
      int r = it * 16 + (tid >> 5);
      int cb = (tid & 31) * 8;
      int grow = mbase + c2 * 128 + r;
      if (grow < TOK)
        *(uint4*)(outp + (size_t)grow * KHD + nbase + cb) =
            *(const uint4*)(cbuf + r * 256 + cb);
    }
    __syncthreads();
  }
}

// ------- reduce 3 partials + bias -> q; RMSNorm; 3-key softmax -> acoef ------
// wave = token, lane = dim-in-head. Packed 4-value butterfly reduce.
__global__ __launch_bounds__(256) void k_qattn(const ushort_t* __restrict__ part,
    const float* __restrict__ qb, const float* __restrict__ kn,
    const float* __restrict__ qnw, float* __restrict__ acoef){
  int wid = threadIdx.x >> 6, lane = threadIdx.x & 63;
  int m = blockIdx.x * 4 + wid;             // 2640 * 4 = 10560 exact
  const ushort_t* p0 = part + (size_t)m * KHD;
  const ushort_t* p1 = p0 + (size_t)TOK * KHD;
  const ushort_t* p2 = p1 + (size_t)TOK * KHD;
  float qwv = qnw[lane];
  for (int h = 0; h < 16; ++h){
    int ib = h * 64 + lane;
    float q = bf2f(p0[ib]) + bf2f(p1[ib]) + bf2f(p2[ib]) + qb[ib];
    float pk = q * qwv;
    float r0 = q * q;
    float r1 = pk * kn[ib];
    float r2 = pk * kn[1024 + ib];
    float r3 = pk * kn[2048 + ib];
    #pragma unroll
    for (int off = 32; off > 0; off >>= 1){
      r0 += __shfl_xor(r0, off, 64);
      r1 += __shfl_xor(r1, off, 64);
      r2 += __shfl_xor(r2, off, 64);
      r3 += __shfl_xor(r3, off, 64);
    }
    float rs = rsqrtf(r0 * (1.f/64.f) + 1e-6f) * 0.125f;
    float s0 = r1 * rs, s1 = r2 * rs, s2 = r3 * rs;
    float mx = fmaxf(s0, fmaxf(s1, s2));
    float e0 = __expf(s0 - mx), e1 = __expf(s1 - mx), e2 = __expf(s2 - mx);
    float inv = 1.f / (e0 + e1 + e2);
    if (lane == 0){
      float2 a12 = {e1 * inv, e2 * inv};
      *(float2*)(acoef + (size_t)m * 32 + h * 2) = a12;
    }
  }
}

// ------- U[h*3+l][c] = sum_d v[l,h,d] * out_w[h*64+d][c]  (48 x 3072, f32) ---
__global__ __launch_bounds__(512) void k_uv(const float* __restrict__ vv,
    const float* __restrict__ ow, float* __restrict__ U){
  int b = blockIdx.x;             // 48 i * 6 cchunk = 288
  int i = b / 6, cc = b % 6;
  int h = i / 3, l = i % 3;
  int c = cc * 512 + threadIdx.x;
  const float* vp = vv + l * 1024 + h * 64;
  const float* wp = ow + (size_t)(h * 64) * 3072 + c;
  float acc = 0.f;
  #pragma unroll
  for (int d = 0; d < 64; ++d) acc += vp[d] * wp[(size_t)d * 3072];
  U[(size_t)i * 3072 + c] = acc;
}

// ------- base[c] = ob[c] + sum_h U[h*3][c];  D[h*2+l'][c] = U[h*3+1+l']-U[h*3]
__global__ __launch_bounds__(256) void k_ubase(const float* __restrict__ U,
    const float* __restrict__ ob, float* __restrict__ base, float* __restrict__ D){
  int c = blockIdx.x * 256 + threadIdx.x;   // 12 blocks
  float b = ob[c];
  #pragma unroll
  for (int h = 0; h < 16; ++h){
    float u0 = U[(size_t)(h * 3 + 0) * 3072 + c];
    float u1 = U[(size_t)(h * 3 + 1) * 3072 + c];
    float u2 = U[(size_t)(h * 3 + 2) * 3072 + c];
    b += u0;
    D[(size_t)(h * 2 + 0) * 3072 + c] = u1 - u0;
    D[(size_t)(h * 2 + 1) * 3072 + c] = u2 - u0;
  }
  base[c] = b;
}

// ------- out = x + base + acoef32 @ D   (rank-32 f32 update, 2 cols/thread) --
__global__ __launch_bounds__(256) void k_rank32(const float* __restrict__ x,
    const float* __restrict__ acoef, const float* __restrict__ D,
    const float* __restrict__ base, float* __restrict__ out){
  __shared__ __align__(16) float as[120][32];
  const int tid = threadIdx.x;
  const int cc = blockIdx.x % 6, ms = blockIdx.x / 6;
  const int c = cc * 512 + tid * 2;
  const int t0 = ms * 120;

  for (int idx = tid; idx < 1920; idx += 256)
    ((float2*)as)[idx] = ((const float2*)(acoef + (size_t)t0 * 32))[idx];

  float ur0[32], ur1[32];
  #pragma unroll
  for (int i = 0; i < 32; ++i){
    float2 d2 = *(const float2*)(D + (size_t)i * 3072 + c);
    ur0[i] = d2.x; ur1[i] = d2.y;
  }
  float2 b2 = *(const float2*)(base + c);
  __syncthreads();

  #pragma unroll 2
  for (int r = 0; r < 120; ++r){
    const size_t o = (size_t)(t0 + r) * 3072 + c;
    float2 xv = *(const float2*)(x + o);
    float a0 = 0.f, a1 = 0.f;
    const f32x4* ap = (const f32x4*)as[r];
    #pragma unroll
    for (int k = 0; k < 8; ++k){
      f32x4 a4 = ap[k];              // LDS broadcast (same addr all lanes)
      a0 += a4[0]*ur0[4*k] + a4[1]*ur0[4*k+1] + a4[2]*ur0[4*k+2] + a4[3]*ur0[4*k+3];
      a1 += a4[0]*ur1[4*k] + a4[1]*ur1[4*k+1] + a4[2]*ur1[4*k+2] + a4[3]*ur1[4*k+3];
    }
    float2 ov = {xv.x + b2.x + a0, xv.y + b2.y + a1};
    *(float2*)(out + o) = ov;
  }
}

extern "C" void kernel_launch(void* const* d_in, const int* in_sizes, int n_in,
                              void* d_out, int out_size, void* d_ws, size_t ws_size,
                              hipStream_t stream){
  const float* x    = (const float*)d_in[0];
  const float* cond = (const float*)d_in[1];
  const float* mew1 = (const float*)d_in[2];
  const float* meb1 = (const float*)d_in[3];
  const float* mew2 = (const float*)d_in[4];
  const float* meb2 = (const float*)d_in[5];
  const float* qw   = (const float*)d_in[6];
  const float* qb   = (const float*)d_in[7];
  const float* kvw  = (const float*)d_in[8];
  const float* kvb  = (const float*)d_in[9];
  const float* qnw  = (const float*)d_in[10];
  const float* knw  = (const float*)d_in[11];
  const float* ow   = (const float*)d_in[12];
  const float* ob   = (const float*)d_in[13];

  char* ws = (char*)d_ws;
  float*    emb    = (float*)(ws + 0);          // 16x512 f32
  float*    kvpart = (float*)(ws + 32768);      // 16x6144 f32
  float*    kn     = (float*)(ws + 425984);     // 3x1024 f32
  float*    vv     = (float*)(ws + 438272);     // 3x1024 f32
  ushort_t* qwt    = (ushort_t*)(ws + 450560);  // [1024][3072] bf16
  float*    U      = (float*)(ws + 6742016);    // [48][3072] f32
  float*    base   = (float*)(ws + 7331840);    // [3072] f32
  float*    Dbuf   = (float*)(ws + 7344128);    // [32][3072] f32
  float*    acoef  = (float*)(ws + 7737344);    // [10560][32] f32
  float*    h1buf  = (float*)(ws + 9089024);    // 16x512 f32

  // d_out hosts: [0, 65MB) xb (bf16 x), [65MB, 130MB) Q partials [3][TOK][1024]
  // bf16 — exact fit (TOK*3072*2 + 3*TOK*1024*2 = TOK*3072*4 = out bytes).
  // k_rank32 fully overwrites d_out at the end of every call.
  ushort_t* xb    = (ushort_t*)d_out;
  ushort_t* qpart = xb + (size_t)TOK * CIMG;

  k_pre1<<<8, 256, 0, stream>>>(cond, mew1, meb1, h1buf);
  k_pre2<<<32, 256, 0, stream>>>(h1buf, mew2, meb2, emb);
  k_kv<<<384, 256, 0, stream>>>(emb, kvw, kvpart);
  k_knorm<<<1, 256, 0, stream>>>(kvpart, kvb, knw, kn, vv);
  k_uv<<<288, 512, 0, stream>>>(vv, ow, U);
  k_ubase<<<12, 256, 0, stream>>>(U, ob, base, Dbuf);
  k_tconv<<<3072, 256, 0, stream>>>(qw, qwt, 3072, 1024);
  k_xconv<<<2048, 256, 0, stream>>>(x, xb, (TOK * CIMG) / 4);
  gemm_splitk<<<504, 512, 0, stream>>>(xb, qwt, qpart);
  k_qattn<<<2640, 256, 0, stream>>>(qpart, qb, kn, qnw, acoef);
  k_rank32<<<88 * 6, 256, 0, stream>>>(x, acoef, Dbuf, base, (float*)d_out);
}

// Round 11
// 310.087 us; speedup vs baseline: 1.0792x; 1.0792x over previous
//
#include <hip/hip_runtime.h>

#define TOK  10560
#define CIMG 3072
#define KHD  1024

typedef unsigned short ushort_t;
typedef unsigned int u32;
using bf16x8 = __attribute__((ext_vector_type(8))) __bf16;
using f32x4  = __attribute__((ext_vector_type(4))) float;

#define GLD_LDS16(gp, lp) __builtin_amdgcn_global_load_lds( \
    (const __attribute__((address_space(1))) u32*)(gp), \
    (__attribute__((address_space(3))) u32*)(lp), 16, 0, 0)

static __device__ __forceinline__ unsigned short f2bf(float f){
  union { float f; unsigned u; } x; x.f = f;
  unsigned r = x.u + 0x7fffu + ((x.u >> 16) & 1u);
  return (unsigned short)(r >> 16);
}
static __device__ __forceinline__ float wave_sum(float v){
  #pragma unroll
  for (int off = 32; off > 0; off >>= 1) v += __shfl_xor(v, off, 64);
  return v;
}

// ---------------- conditioning MLP layer 1: h1 = silu(cp@w1+b1) --------------
__global__ __launch_bounds__(256) void k_pre1(const float* __restrict__ cond,
    const float* __restrict__ w1, const float* __restrict__ b1,
    float* __restrict__ h1){
  __shared__ float cs[16][16];
  int t = threadIdx.x;
  if (t < 256) cs[t >> 4][t & 15] = cond[(64 + (t >> 4)) * 16 + (t & 15)];
  __syncthreads();
  #pragma unroll
  for (int i = 0; i < 4; ++i){
    int idx = blockIdx.x * 256 + t + i * 2048;
    int r = idx >> 9, c = idx & 511;
    float s = b1[c];
    #pragma unroll
    for (int j = 0; j < 16; ++j) s += cs[r][j] * w1[j * 512 + c];
    h1[idx] = s / (1.f + __expf(-s));   // silu
  }
}

// ---------------- conditioning MLP layer 2: emb = h1@w2 + b2 -----------------
__global__ __launch_bounds__(256) void k_pre2(const float* __restrict__ h1,
    const float* __restrict__ w2, const float* __restrict__ b2,
    float* __restrict__ emb){
  int idx = blockIdx.x * 256 + threadIdx.x;
  int r = idx >> 9, c = idx & 511;
  const float* hp = h1 + r * 512;
  const float* wp = w2 + c;
  float acc = b2[c];
  #pragma unroll 8
  for (int j = 0; j < 512; ++j) acc += hp[j] * wp[(size_t)j * 512];
  emb[idx] = acc;
}

// ---------------- kv = mf @ kv_w, split-K partials (deterministic) ----------
__global__ __launch_bounds__(256) void k_kv(const float* __restrict__ emb,
                                            const float* __restrict__ kvw,
                                            float* __restrict__ part){
  int bl = blockIdx.x;                 // 3 l * 8 ntile * 16 kchunk = 384
  int l = bl / 128, rem = bl % 128, nt = rem / 16, kc = rem % 16;
  int n = nt * 256 + threadIdx.x;
  const float* e = emb + 2048 * l + kc * 256;   // mf[l][r] = emb[2048l + r]
  const float* w = kvw + (size_t)(kc * 256) * 2048 + n;
  float acc = 0.f;
  for (int r = 0; r < 256; ++r) acc += e[r] * w[(size_t)r * 2048];
  part[kc * 6144 + l * 2048 + n] = acc;
}

// ---------------- reduce partials, bias, k-RMSNorm ---------------------------
__global__ void k_knorm(const float* __restrict__ part, const float* __restrict__ kvb,
                        const float* __restrict__ knw, float* __restrict__ kn,
                        float* __restrict__ vv){
  int wid = threadIdx.x >> 6, lane = threadIdx.x & 63;
  for (int i = 0; i < 12; ++i){
    int g = wid * 12 + i;               // 0..47 = (l,h)
    int l = g >> 4, h = g & 15;
    int ik = l * 2048 + h * 64 + lane;
    float kk = kvb[h * 64 + lane];
    float v  = kvb[1024 + h * 64 + lane];
    for (int p = 0; p < 16; ++p){ kk += part[p * 6144 + ik]; v += part[p * 6144 + ik + 1024]; }
    float ss = wave_sum(kk * kk);
    kn[l * 1024 + h * 64 + lane] = kk * rsqrtf(ss * (1.f/64.f) + 1e-6f) * knw[lane];
    vv[l * 1024 + h * 64 + lane] = v;
  }
}

// ---------------- transpose + f32->bf16 weight convert: dst[C][R] ------------
__global__ __launch_bounds__(256) void k_tconv(const float* __restrict__ src,
                                               ushort_t* __restrict__ dst,
                                               int R, int C){
  __shared__ float tile[32][33];
  int nTr = R >> 5;
  int tr = blockIdx.x % nTr, tc = blockIdx.x / nTr;
  int r0 = tr * 32, c0 = tc * 32, t = threadIdx.x;
  #pragma unroll
  for (int i = 0; i < 4; ++i){
    int idx = t + i * 256; int r = idx >> 5, c = idx & 31;
    tile[r][c] = src[(size_t)(r0 + r) * C + c0 + c];
  }
  __syncthreads();
  #pragma unroll
  for (int i = 0; i < 4; ++i){
    int idx = t + i * 256; int rr = idx >> 5, cc = idx & 31;
    dst[(size_t)(c0 + rr) * R + r0 + cc] = f2bf(tile[cc][rr]);
  }
}

// ---------------- x f32 -> bf16 streaming convert ----------------------------
__global__ __launch_bounds__(256) void k_xconv(const float* __restrict__ x,
                                               ushort_t* __restrict__ xb, int n4){
  for (int i = blockIdx.x * 256 + threadIdx.x; i < n4; i += gridDim.x * 256){
    float4 v = ((const float4*)x)[i];
    ushort4 o;
    o.x = f2bf(v.x); o.y = f2bf(v.y); o.z = f2bf(v.z); o.w = f2bf(v.w);
    ((ushort4*)xb)[i] = o;
  }
}

// ======== 256x256 bf16 MFMA Q-GEMM, 8-phase schedule, FUSED attention ========
// (round-9 kernel, passing @139us)
__global__ __launch_bounds__(512, 2) void gemm_fused(
    const ushort_t* __restrict__ A, const ushort_t* __restrict__ Bt,
    int Mdim, int Kdim, int Ndim,
    const float* __restrict__ bias, const float* __restrict__ kn,
    const float* __restrict__ qnw, float* __restrict__ acoef){
  __shared__ __align__(16) unsigned char lds[131072];
  const int tid = threadIdx.x;
  const int lane = tid & 63, wid = tid >> 6;
  const int wm = wid >> 2, wn = wid & 3;     // 2 x 4 waves -> per-wave 128x64
  const int l15 = lane & 15, kg = lane >> 4;
  const int ntiles = Ndim >> 8;

  int bid = blockIdx.x;
  const int cpx = gridDim.x >> 3;
  bid = (bid & 7) * cpx + (bid >> 3);
  const int mt = bid / ntiles, nt = bid % ntiles;
  const int mbase = mt << 8, nbase = nt << 8;

  const int sr  = tid >> 1;                       // 0..255
  const int skh = (tid & 1) ^ ((sr >> 2) & 1);    // inverse swizzle on source
  int arow = mbase + sr; if (arow >= Mdim) arow = Mdim - 1;
  const ushort_t* gA = A  + (size_t)arow * Kdim + skh * 8;
  const ushort_t* gB = Bt + (size_t)(nbase + sr) * Kdim + skh * 8;
  const int wofs = wid * 1024;

  auto stage = [&](int t, int c, int b){
    const int gk = t * 64 + c * 16;
    unsigned char* dst = lds + b * 65536 + c * 8192 + wofs;
    GLD_LDS16(gA + gk, dst);
    GLD_LDS16(gB + gk, dst + 32768);
  };

  const int arl = wm * 128 + l15;
  const int brl = wn * 64 + l15;
  const int kh  = ((kg & 1) ^ ((l15 >> 2) & 1)) * 16;
  const unsigned aBase = (unsigned)((kg >> 1) * 8192 + arl * 32 + kh);
  const unsigned bBase = (unsigned)(32768 + (kg >> 1) * 8192 + brl * 32 + kh);

  f32x4 acc[8][4];
  #pragma unroll
  for (int m = 0; m < 8; ++m)
    #pragma unroll
    for (int n = 0; n < 4; ++n) acc[m][n] = {0.f, 0.f, 0.f, 0.f};

  bf16x8 afr[4], bfr[4];

#define PH_READ_B(base, KSL) { _Pragma("unroll") \
    for (int n = 0; n < 4; ++n) \
      bfr[n] = *(const bf16x8*)((base) + bBase + (KSL)*16384 + n*512); }
#define PH_READ_A(base, KSL, M0) { _Pragma("unroll") \
    for (int m = 0; m < 4; ++m) \
      afr[m] = *(const bf16x8*)((base) + aBase + (KSL)*16384 + ((M0)+m)*512); }
#define PH_MFMA(R0) { __builtin_amdgcn_s_setprio(1); _Pragma("unroll") \
    for (int m = 0; m < 4; ++m){ _Pragma("unroll") \
      for (int n = 0; n < 4; ++n) \
        acc[(R0)+m][n] = __builtin_amdgcn_mfma_f32_16x16x32_bf16(afr[m], bfr[n], acc[(R0)+m][n], 0, 0, 0); } \
    __builtin_amdgcn_s_setprio(0); }

  const int T = Kdim >> 6;

  stage(0, 0, 0); stage(0, 1, 0); stage(0, 2, 0); stage(0, 3, 0);
  asm volatile("s_waitcnt vmcnt(4)" ::: "memory");
  __builtin_amdgcn_s_barrier();

  for (int t = 0; t < T - 1; ++t){
    const int b = t & 1;
    const unsigned char* base = lds + b * 65536;
    PH_READ_B(base, 0); PH_READ_A(base, 0, 0);
    stage(t + 1, 0, b ^ 1);
    __builtin_amdgcn_s_barrier();
    PH_MFMA(0);
    __builtin_amdgcn_s_barrier();
    PH_READ_A(base, 0, 4);
    stage(t + 1, 1, b ^ 1);
    asm volatile("s_waitcnt vmcnt(4)" ::: "memory");
    __builtin_amdgcn_s_barrier();
    PH_MFMA(4);
    __builtin_amdgcn_s_barrier();
    PH_READ_B(base, 1); PH_READ_A(base, 1, 0);
    stage(t + 1, 2, b ^ 1);
    __builtin_amdgcn_s_barrier();
    PH_MFMA(0);
    __builtin_amdgcn_s_barrier();
    PH_READ_A(base, 1, 4);
    stage(t + 1, 3, b ^ 1);
    asm volatile("s_waitcnt vmcnt(4)" ::: "memory");
    __builtin_amdgcn_s_barrier();
    PH_MFMA(4);
    __builtin_amdgcn_s_barrier();
  }
  {
    const unsigned char* base = lds + ((T - 1) & 1) * 65536;
    PH_READ_B(base, 0); PH_READ_A(base, 0, 0);
    __builtin_amdgcn_s_barrier();
    PH_MFMA(0);
    __builtin_amdgcn_s_barrier();
    PH_READ_A(base, 0, 4);
    asm volatile("s_waitcnt vmcnt(0)" ::: "memory");
    __builtin_amdgcn_s_barrier();
    PH_MFMA(4);
    __builtin_amdgcn_s_barrier();
    PH_READ_B(base, 1); PH_READ_A(base, 1, 0);
    PH_MFMA(0);
    PH_READ_A(base, 1, 4);
    PH_MFMA(4);
  }
#undef PH_READ_B
#undef PH_READ_A
#undef PH_MFMA

  // -------- fused attention epilogue (no LDS, no Qbuf) --------
  const int hglob = nt * 4 + wn;            // global head, 0..15
  float qnwv[4], qbv[4], knv0[4], knv1[4], knv2[4];
  #pragma unroll
  for (int n = 0; n < 4; ++n){
    int d = n * 16 + l15;
    qnwv[n] = qnw[d];
    qbv[n]  = bias[nbase + wn * 64 + d];
    knv0[n] = kn[hglob * 64 + d];
    knv1[n] = kn[1024 + hglob * 64 + d];
    knv2[n] = kn[2048 + hglob * 64 + d];
  }
  #pragma unroll
  for (int m = 0; m < 8; ++m){
    #pragma unroll
    for (int j = 0; j < 4; ++j){
      // kg-group 'kg' owns row r = m*16 + kg*4 + j
      float q[4], ssq = 0.f;
      #pragma unroll
      for (int n = 0; n < 4; ++n){ q[n] = acc[m][n][j] + qbv[n]; ssq += q[n] * q[n]; }
      #pragma unroll
      for (int off = 1; off < 16; off <<= 1) ssq += __shfl_xor(ssq, off, 64);
      float rs = rsqrtf(ssq * (1.f/64.f) + 1e-6f);
      float s0 = 0.f, s1 = 0.f, s2 = 0.f;
      #pragma unroll
      for (int n = 0; n < 4; ++n){
        float qn = q[n] * rs * qnwv[n];
        s0 += qn * knv0[n]; s1 += qn * knv1[n]; s2 += qn * knv2[n];
      }
      #pragma unroll
      for (int off = 1; off < 16; off <<= 1){
        s0 += __shfl_xor(s0, off, 64);
        s1 += __shfl_xor(s1, off, 64);
        s2 += __shfl_xor(s2, off, 64);
      }
      s0 *= 0.125f; s1 *= 0.125f; s2 *= 0.125f;
      float mx = fmaxf(s0, fmaxf(s1, s2));
      float e0 = __expf(s0 - mx), e1 = __expf(s1 - mx), e2 = __expf(s2 - mx);
      float inv = 1.f / (e0 + e1 + e2);
      int grow = mbase + wm * 128 + m * 16 + kg * 4 + j;
      if (l15 == 0 && grow < Mdim){
        float2 a12 = {e1 * inv, e2 * inv};
        *(float2*)(acoef + (size_t)grow * 32 + hglob * 2) = a12;
      }
    }
  }
}

// ------- U[h*3+l][c] = sum_d v[l,h,d] * out_w[h*64+d][c]  (48 x 3072, f32) ---
__global__ __launch_bounds__(512) void k_uv(const float* __restrict__ vv,
    const float* __restrict__ ow, float* __restrict__ U){
  int b = blockIdx.x;             // 48 i * 6 cchunk = 288
  int i = b / 6, cc = b % 6;
  int h = i / 3, l = i % 3;
  int c = cc * 512 + threadIdx.x;
  const float* vp = vv + l * 1024 + h * 64;
  const float* wp = ow + (size_t)(h * 64) * 3072 + c;
  float acc = 0.f;
  #pragma unroll
  for (int d = 0; d < 64; ++d) acc += vp[d] * wp[(size_t)d * 3072];
  U[(size_t)i * 3072 + c] = acc;
}

// ------- base[c] = ob[c] + sum_h U[h*3][c];  D[h*2+l'][c] = U[h*3+1+l']-U[h*3]
__global__ __launch_bounds__(256) void k_ubase(const float* __restrict__ U,
    const float* __restrict__ ob, float* __restrict__ base, float* __restrict__ D){
  int c = blockIdx.x * 256 + threadIdx.x;   // 12 blocks
  float b = ob[c];
  #pragma unroll
  for (int h = 0; h < 16; ++h){
    float u0 = U[(size_t)(h * 3 + 0) * 3072 + c];
    float u1 = U[(size_t)(h * 3 + 1) * 3072 + c];
    float u2 = U[(size_t)(h * 3 + 2) * 3072 + c];
    b += u0;
    D[(size_t)(h * 2 + 0) * 3072 + c] = u1 - u0;
    D[(size_t)(h * 2 + 1) * 3072 + c] = u2 - u0;
  }
  base[c] = b;
}

// ------- out = x + base + acoef32 @ D   (rank-32 f32 update) -----------------
// a-row loads are wave-uniform -> scalar (s_load) pipe, SGPR-broadcast FMA.
// No LDS -> high occupancy; x/out streamed float2 per lane.
__global__ __launch_bounds__(256) void k_rank32(const float* __restrict__ x,
    const float* __restrict__ acoef, const float* __restrict__ D,
    const float* __restrict__ base, float* __restrict__ out){
  const int tid = threadIdx.x;
  const int cc = blockIdx.x % 6, ms = blockIdx.x / 6;
  const int c = cc * 512 + tid * 2;
  const int t0 = ms * 120;

  float ur0[32], ur1[32];
  #pragma unroll
  for (int i = 0; i < 32; ++i){
    float2 d2 = *(const float2*)(D + (size_t)i * 3072 + c);
    ur0[i] = d2.x; ur1[i] = d2.y;
  }
  float2 b2 = *(const float2*)(base + c);
  const float* ap = acoef + (size_t)t0 * 32;

  #pragma unroll 2
  for (int r = 0; r < 120; ++r){
    const size_t o = (size_t)(t0 + r) * 3072 + c;
    float2 xv = *(const float2*)(x + o);
    float a0 = 0.f, a1 = 0.f;
    #pragma unroll
    for (int k = 0; k < 32; ++k){
      float av = ap[r * 32 + k];        // uniform -> SGPR broadcast
      a0 += av * ur0[k];
      a1 += av * ur1[k];
    }
    float2 ov = {xv.x + b2.x + a0, xv.y + b2.y + a1};
    *(float2*)(out + o) = ov;
  }
}

extern "C" void kernel_launch(void* const* d_in, const int* in_sizes, int n_in,
                              void* d_out, int out_size, void* d_ws, size_t ws_size,
                              hipStream_t stream){
  const float* x    = (const float*)d_in[0];
  const float* cond = (const float*)d_in[1];
  const float* mew1 = (const float*)d_in[2];
  const float* meb1 = (const float*)d_in[3];
  const float* mew2 = (const float*)d_in[4];
  const float* meb2 = (const float*)d_in[5];
  const float* qw   = (const float*)d_in[6];
  const float* qb   = (const float*)d_in[7];
  const float* kvw  = (const float*)d_in[8];
  const float* kvb  = (const float*)d_in[9];
  const float* qnw  = (const float*)d_in[10];
  const float* knw  = (const float*)d_in[11];
  const float* ow   = (const float*)d_in[12];
  const float* ob   = (const float*)d_in[13];

  char* ws = (char*)d_ws;
  float*    emb    = (float*)(ws + 0);          // 16x512 f32
  float*    kvpart = (float*)(ws + 32768);      // 16x6144 f32
  float*    kn     = (float*)(ws + 425984);     // 3x1024 f32
  float*    vv     = (float*)(ws + 438272);     // 3x1024 f32
  ushort_t* qwt    = (ushort_t*)(ws + 450560);  // [1024][3072] bf16
  float*    U      = (float*)(ws + 6742016);    // [48][3072] f32
  float*    base   = (float*)(ws + 7331840);    // [3072] f32
  float*    Dbuf   = (float*)(ws + 7344128);    // [32][3072] f32
  float*    acoef  = (float*)(ws + 7737344);    // [10560][32] f32
  float*    h1buf  = (float*)(ws + 9089024);    // 16x512 f32

  // xb (bf16 x) lives in d_out: needed only until the Q-GEMM; k_rank32
  // fully overwrites d_out at the end of every call.
  ushort_t* xb = (ushort_t*)d_out;

  k_pre1<<<8, 256, 0, stream>>>(cond, mew1, meb1, h1buf);
  k_pre2<<<32, 256, 0, stream>>>(h1buf, mew2, meb2, emb);
  k_kv<<<384, 256, 0, stream>>>(emb, kvw, kvpart);
  k_knorm<<<1, 256, 0, stream>>>(kvpart, kvb, knw, kn, vv);
  k_uv<<<288, 512, 0, stream>>>(vv, ow, U);
  k_ubase<<<12, 256, 0, stream>>>(U, ob, base, Dbuf);
  k_tconv<<<3072, 256, 0, stream>>>(qw, qwt, 3072, 1024);
  k_xconv<<<2048, 256, 0, stream>>>(x, xb, (TOK * CIMG) / 4);
  gemm_fused<<<42 * 4, 512, 0, stream>>>(xb, qwt, TOK, CIMG, KHD, qb, kn, qnw, acoef);
  k_rank32<<<88 * 6, 256, 0, stream>>>(x, acoef, Dbuf, base, (float*)d_out);
}

// Round 12
// 307.406 us; speedup vs baseline: 1.0886x; 1.0087x over previous
//
#include <hip/hip_runtime.h>

#define TOK  10560
#define CIMG 3072
#define KHD  1024

typedef unsigned short ushort_t;
typedef unsigned int u32;
using bf16x8 = __attribute__((ext_vector_type(8))) __bf16;
using f32x4  = __attribute__((ext_vector_type(4))) float;

#define GLD_LDS16(gp, lp) __builtin_amdgcn_global_load_lds( \
    (const __attribute__((address_space(1))) u32*)(gp), \
    (__attribute__((address_space(3))) u32*)(lp), 16, 0, 0)

static __device__ __forceinline__ unsigned short f2bf(float f){
  union { float f; unsigned u; } x; x.f = f;
  unsigned r = x.u + 0x7fffu + ((x.u >> 16) & 1u);
  return (unsigned short)(r >> 16);
}
static __device__ __forceinline__ float wave_sum(float v){
  #pragma unroll
  for (int off = 32; off > 0; off >>= 1) v += __shfl_xor(v, off, 64);
  return v;
}

// ---------------- conditioning MLP layer 1: h1 = silu(cp@w1+b1) --------------
__global__ __launch_bounds__(256) void k_pre1(const float* __restrict__ cond,
    const float* __restrict__ w1, const float* __restrict__ b1,
    float* __restrict__ h1){
  __shared__ float cs[16][16];
  int t = threadIdx.x;
  if (t < 256) cs[t >> 4][t & 15] = cond[(64 + (t >> 4)) * 16 + (t & 15)];
  __syncthreads();
  #pragma unroll
  for (int i = 0; i < 4; ++i){
    int idx = blockIdx.x * 256 + t + i * 2048;
    int r = idx >> 9, c = idx & 511;
    float s = b1[c];
    #pragma unroll
    for (int j = 0; j < 16; ++j) s += cs[r][j] * w1[j * 512 + c];
    h1[idx] = s / (1.f + __expf(-s));   // silu
  }
}

// ---------------- conditioning MLP layer 2: emb = h1@w2 + b2 -----------------
__global__ __launch_bounds__(256) void k_pre2(const float* __restrict__ h1,
    const float* __restrict__ w2, const float* __restrict__ b2,
    float* __restrict__ emb){
  int idx = blockIdx.x * 256 + threadIdx.x;
  int r = idx >> 9, c = idx & 511;
  const float* hp = h1 + r * 512;
  const float* wp = w2 + c;
  float acc = b2[c];
  #pragma unroll 8
  for (int j = 0; j < 512; ++j) acc += hp[j] * wp[(size_t)j * 512];
  emb[idx] = acc;
}

// ---------------- kv = mf @ kv_w, split-K partials (deterministic) ----------
__global__ __launch_bounds__(256) void k_kv(const float* __restrict__ emb,
                                            const float* __restrict__ kvw,
                                            float* __restrict__ part){
  int bl = blockIdx.x;                 // 3 l * 8 ntile * 16 kchunk = 384
  int l = bl / 128, rem = bl % 128, nt = rem / 16, kc = rem % 16;
  int n = nt * 256 + threadIdx.x;
  const float* e = emb + 2048 * l + kc * 256;   // mf[l][r] = emb[2048l + r]
  const float* w = kvw + (size_t)(kc * 256) * 2048 + n;
  float acc = 0.f;
  for (int r = 0; r < 256; ++r) acc += e[r] * w[(size_t)r * 2048];
  part[kc * 6144 + l * 2048 + n] = acc;
}

// ---------------- reduce partials, bias, k-RMSNorm ---------------------------
__global__ void k_knorm(const float* __restrict__ part, const float* __restrict__ kvb,
                        const float* __restrict__ knw, float* __restrict__ kn,
                        float* __restrict__ vv){
  int wid = threadIdx.x >> 6, lane = threadIdx.x & 63;
  for (int i = 0; i < 12; ++i){
    int g = wid * 12 + i;               // 0..47 = (l,h)
    int l = g >> 4, h = g & 15;
    int ik = l * 2048 + h * 64 + lane;
    float kk = kvb[h * 64 + lane];
    float v  = kvb[1024 + h * 64 + lane];
    for (int p = 0; p < 16; ++p){ kk += part[p * 6144 + ik]; v += part[p * 6144 + ik + 1024]; }
    float ss = wave_sum(kk * kk);
    kn[l * 1024 + h * 64 + lane] = kk * rsqrtf(ss * (1.f/64.f) + 1e-6f) * knw[lane];
    vv[l * 1024 + h * 64 + lane] = v;
  }
}

// ---------------- transpose + f32->bf16 weight convert: dst[C][R] ------------
__global__ __launch_bounds__(256) void k_tconv(const float* __restrict__ src,
                                               ushort_t* __restrict__ dst,
                                               int R, int C){
  __shared__ float tile[32][33];
  int nTr = R >> 5;
  int tr = blockIdx.x % nTr, tc = blockIdx.x / nTr;
  int r0 = tr * 32, c0 = tc * 32, t = threadIdx.x;
  #pragma unroll
  for (int i = 0; i < 4; ++i){
    int idx = t + i * 256; int r = idx >> 5, c = idx & 31;
    tile[r][c] = src[(size_t)(r0 + r) * C + c0 + c];
  }
  __syncthreads();
  #pragma unroll
  for (int i = 0; i < 4; ++i){
    int idx = t + i * 256; int rr = idx >> 5, cc = idx & 31;
    dst[(size_t)(c0 + rr) * R + r0 + cc] = f2bf(tile[cc][rr]);
  }
}

// ---------------- x f32 -> bf16 streaming convert ----------------------------
__global__ __launch_bounds__(256) void k_xconv(const float* __restrict__ x,
                                               ushort_t* __restrict__ xb, int n4){
  for (int i = blockIdx.x * 256 + threadIdx.x; i < n4; i += gridDim.x * 256){
    float4 v = ((const float4*)x)[i];
    ushort4 o;
    o.x = f2bf(v.x); o.y = f2bf(v.y); o.z = f2bf(v.z); o.w = f2bf(v.w);
    ((ushort4*)xb)[i] = o;
  }
}

// ======== 192x128 bf16 MFMA Q-GEMM, 8-phase-style, 2 blocks/CU, fused attn ===
// A bf16 [10560][3072], Bt bf16 [1024][3072]. BK=64, 2 phases/K-tile.
// LDS 80KB/block -> exactly 2 blocks/CU (160KB). Grid 55x8 = 440.
// Wave-specialized staging: waves 0-5 stage A (2 loads/phase, vmcnt(2));
// waves 6-7 stage B (4 loads/phase, vmcnt(4)). Ledger: entering tile t,
// each wave's chunks {2,3}(t) outstanding; phaseA waits them, phaseB waits
// chunks {0,1}(t+1). Drain vmcnt(0) only in the peeled last tile.
// 8 waves = 4 (rows, 48 each) x 2 (cols, 64 each); acc[3][4]; head = nt*2+wn.
// Epilogue: fused RMSNorm + 3-key softmax (16-lane shfl), packs a1,a2 -> bf16.
__global__ __launch_bounds__(512, 4) void gemm_fused(
    const ushort_t* __restrict__ A, const ushort_t* __restrict__ Bt,
    const float* __restrict__ bias, const float* __restrict__ kn,
    const float* __restrict__ qnw, u32* __restrict__ acoefb){
  __shared__ __align__(16) unsigned char lds[81920]; // 2 buf x (A 24K + B 16K)
  const int tid = threadIdx.x;
  const int lane = tid & 63, wid = tid >> 6;
  const int wm = wid >> 1, wn = wid & 1;     // 4 x 2 waves -> per-wave 48x64
  const int l15 = lane & 15, kg = lane >> 4;

  // XCD swizzle: 440 = 8 * 55 -> bijective
  int bid = blockIdx.x;
  bid = (bid & 7) * 55 + (bid >> 3);
  const int mt = bid >> 3, nt = bid & 7;
  const int mbase = mt * 192, nbase = nt << 7;

  // A staging (waves 0..5): rows 0..191, 1 load/chunk/thread
  const int sr  = tid >> 1;                       // 0..191 (tid<384)
  const int skh = (tid & 1) ^ ((sr >> 2) & 1);    // inverse swizzle on source
  const ushort_t* gA = A + (size_t)(mbase + sr) * CIMG + skh * 8;
  // B staging (waves 6,7): rows 0..127, 2 loads/chunk/thread
  const int u   = tid - 384;                      // 0..127
  const int skb = (u & 1) ^ ((u >> 3) & 1);
  const ushort_t* gB0 = Bt + (size_t)(nbase + (u >> 1)) * CIMG + skb * 8;
  const ushort_t* gB1 = gB0 + (size_t)64 * CIMG;  // row+64: bit2 same -> same skb

  auto stage = [&](int t, int c, int b){
    const int gk = t * 64 + c * 16;
    if (wid < 6){
      unsigned char* dst = lds + b * 40960 + c * 6144 + wid * 1024;
      GLD_LDS16(gA + gk, dst);
    } else {
      unsigned char* dst = lds + b * 40960 + 24576 + c * 4096 + (wid - 6) * 1024;
      GLD_LDS16(gB0 + gk, dst);
      GLD_LDS16(gB1 + gk, dst + 2048);
    }
  };
#define WAITC2 { if (wid < 6) asm volatile("s_waitcnt vmcnt(2)" ::: "memory"); \
                 else         asm volatile("s_waitcnt vmcnt(4)" ::: "memory"); }

  // fragment read bases (A chunks 6144B, B chunks 4096B @ +24576)
  const int arl = wm * 48 + l15;
  const int brl = wn * 64 + l15;
  const int kh  = ((kg & 1) ^ ((l15 >> 2) & 1)) * 16;
  const unsigned aBase = (unsigned)((kg >> 1) * 6144 + arl * 32 + kh);
  const unsigned bBase = (unsigned)(24576 + (kg >> 1) * 4096 + brl * 32 + kh);

  f32x4 acc[3][4];
  #pragma unroll
  for (int m = 0; m < 3; ++m)
    #pragma unroll
    for (int n = 0; n < 4; ++n) acc[m][n] = {0.f, 0.f, 0.f, 0.f};

  bf16x8 afr[3], bfr[4];

#define PH_READ(base, KSL) { _Pragma("unroll") \
    for (int n = 0; n < 4; ++n) \
      bfr[n] = *(const bf16x8*)((base) + bBase + (KSL)*8192 + n*512); \
    _Pragma("unroll") \
    for (int m = 0; m < 3; ++m) \
      afr[m] = *(const bf16x8*)((base) + aBase + (KSL)*12288 + m*512); }
#define PH_MFMA { __builtin_amdgcn_s_setprio(1); _Pragma("unroll") \
    for (int m = 0; m < 3; ++m){ _Pragma("unroll") \
      for (int n = 0; n < 4; ++n) \
        acc[m][n] = __builtin_amdgcn_mfma_f32_16x16x32_bf16(afr[m], bfr[n], acc[m][n], 0, 0, 0); } \
    __builtin_amdgcn_s_setprio(0); }

  const int T = CIMG / 64;   // 48

  stage(0, 0, 0); stage(0, 1, 0); stage(0, 2, 0); stage(0, 3, 0);
  WAITC2;                      // chunks 0,1 of tile 0 landed
  __builtin_amdgcn_s_barrier();

  for (int t = 0; t < T - 1; ++t){
    const int b = t & 1;
    const unsigned char* base = lds + b * 40960;
    // phase A: ksl0
    PH_READ(base, 0);
    stage(t + 1, 0, b ^ 1); stage(t + 1, 1, b ^ 1);
    WAITC2;                    // chunks 2,3 of t landed
    __builtin_amdgcn_s_barrier();
    PH_MFMA;
    __builtin_amdgcn_s_barrier();
    // phase B: ksl1
    PH_READ(base, 1);
    stage(t + 1, 2, b ^ 1); stage(t + 1, 3, b ^ 1);
    WAITC2;                    // chunks 0,1 of t+1 landed
    __builtin_amdgcn_s_barrier();
    PH_MFMA;
    __builtin_amdgcn_s_barrier();
  }
  { // peeled last tile
    const unsigned char* base = lds + ((T - 1) & 1) * 40960;
    PH_READ(base, 0);
    asm volatile("s_waitcnt vmcnt(0)" ::: "memory");
    __builtin_amdgcn_s_barrier();
    PH_MFMA;
    __builtin_amdgcn_s_barrier();
    PH_READ(base, 1);
    PH_MFMA;
  }
#undef PH_READ
#undef PH_MFMA
#undef WAITC2

  // -------- fused attention epilogue (registers + 16-lane shfl only) --------
  const int hglob = nt * 2 + wn;            // global head, 0..15
  float qnwv[4], qbv[4], knv0[4], knv1[4], knv2[4];
  #pragma unroll
  for (int n = 0; n < 4; ++n){
    int d = n * 16 + l15;
    qnwv[n] = qnw[d];
    qbv[n]  = bias[nbase + wn * 64 + d];
    knv0[n] = kn[hglob * 64 + d];
    knv1[n] = kn[1024 + hglob * 64 + d];
    knv2[n] = kn[2048 + hglob * 64 + d];
  }
  #pragma unroll
  for (int m = 0; m < 3; ++m){
    #pragma unroll
    for (int j = 0; j < 4; ++j){
      float q[4], ssq = 0.f;
      #pragma unroll
      for (int n = 0; n < 4; ++n){ q[n] = acc[m][n][j] + qbv[n]; ssq += q[n] * q[n]; }
      #pragma unroll
      for (int off = 1; off < 16; off <<= 1) ssq += __shfl_xor(ssq, off, 64);
      float rs = rsqrtf(ssq * (1.f/64.f) + 1e-6f);
      float s0 = 0.f, s1 = 0.f, s2 = 0.f;
      #pragma unroll
      for (int n = 0; n < 4; ++n){
        float qn = q[n] * rs * qnwv[n];
        s0 += qn * knv0[n]; s1 += qn * knv1[n]; s2 += qn * knv2[n];
      }
      #pragma unroll
      for (int off = 1; off < 16; off <<= 1){
        s0 += __shfl_xor(s0, off, 64);
        s1 += __shfl_xor(s1, off, 64);
        s2 += __shfl_xor(s2, off, 64);
      }
      s0 *= 0.125f; s1 *= 0.125f; s2 *= 0.125f;
      float mx = fmaxf(s0, fmaxf(s1, s2));
      float e0 = __expf(s0 - mx), e1 = __expf(s1 - mx), e2 = __expf(s2 - mx);
      float inv = 1.f / (e0 + e1 + e2);
      int grow = mbase + wm * 48 + m * 16 + kg * 4 + j;   // < 10560 always
      if (l15 == 0){
        u32 pk = (u32)f2bf(e1 * inv) | ((u32)f2bf(e2 * inv) << 16);
        acoefb[(size_t)grow * 16 + hglob] = pk;
      }
    }
  }
}

// ------- U[h*3+l][c] = sum_d v[l,h,d] * out_w[h*64+d][c]  (48 x 3072, f32) ---
__global__ __launch_bounds__(512) void k_uv(const float* __restrict__ vv,
    const float* __restrict__ ow, float* __restrict__ U){
  int b = blockIdx.x;             // 48 i * 6 cchunk = 288
  int i = b / 6, cc = b % 6;
  int h = i / 3, l = i % 3;
  int c = cc * 512 + threadIdx.x;
  const float* vp = vv + l * 1024 + h * 64;
  const float* wp = ow + (size_t)(h * 64) * 3072 + c;
  float acc = 0.f;
  #pragma unroll
  for (int d = 0; d < 64; ++d) acc += vp[d] * wp[(size_t)d * 3072];
  U[(size_t)i * 3072 + c] = acc;
}

// ------- base[c] = ob[c] + sum_h U[h*3][c];  Dt[c][h*2+l'] = bf16(U diff) ----
__global__ __launch_bounds__(256) void k_ubase(const float* __restrict__ U,
    const float* __restrict__ ob, float* __restrict__ base,
    ushort_t* __restrict__ Dt){
  int c = blockIdx.x * 256 + threadIdx.x;   // 12 blocks
  float b = ob[c];
  #pragma unroll
  for (int h = 0; h < 16; ++h){
    float u0 = U[(size_t)(h * 3 + 0) * 3072 + c];
    float u1 = U[(size_t)(h * 3 + 1) * 3072 + c];
    float u2 = U[(size_t)(h * 3 + 2) * 3072 + c];
    b += u0;
    Dt[(size_t)c * 32 + h * 2 + 0] = f2bf(u1 - u0);
    Dt[(size_t)c * 32 + h * 2 + 1] = f2bf(u2 - u0);
  }
  base[c] = b;
}

// ------- out = x + base + a @ D  via MFMA (K=32), no LDS ---------------------
// a bf16 [10560][32], Dt bf16 [3072][32]. Wave: 16 rows x 512 cols.
// Grid 165 rtiles * 6 cchunks = 990 blocks x 4 waves. Pure streaming + 32 MFMA.
__global__ __launch_bounds__(256) void k_rankmm(const float* __restrict__ x,
    const ushort_t* __restrict__ ab, const ushort_t* __restrict__ Dt,
    const float* __restrict__ base, float* __restrict__ out){
  const int tid = threadIdx.x;
  const int wid = tid >> 6, lane = tid & 63;
  const int l15 = lane & 15, kg = lane >> 4;
  const int rtile = blockIdx.x / 6, cc = blockIdx.x % 6;
  const int row0 = rtile * 64 + wid * 16;    // 165*64 = 10560 exact
  const int col0 = cc * 512;
  bf16x8 afr = *(const bf16x8*)(ab + (size_t)(row0 + l15) * 32 + kg * 8);
  #pragma unroll 4
  for (int ct = 0; ct < 32; ++ct){
    int col = col0 + ct * 16 + l15;
    bf16x8 bfr = *(const bf16x8*)(Dt + (size_t)col * 32 + kg * 8);
    f32x4 acc = {0.f, 0.f, 0.f, 0.f};
    acc = __builtin_amdgcn_mfma_f32_16x16x32_bf16(afr, bfr, acc, 0, 0, 0);
    float bs = base[col];
    #pragma unroll
    for (int j = 0; j < 4; ++j){
      size_t o = (size_t)(row0 + kg * 4 + j) * 3072 + col;
      out[o] = x[o] + bs + acc[j];
    }
  }
}

extern "C" void kernel_launch(void* const* d_in, const int* in_sizes, int n_in,
                              void* d_out, int out_size, void* d_ws, size_t ws_size,
                              hipStream_t stream){
  const float* x    = (const float*)d_in[0];
  const float* cond = (const float*)d_in[1];
  const float* mew1 = (const float*)d_in[2];
  const float* meb1 = (const float*)d_in[3];
  const float* mew2 = (const float*)d_in[4];
  const float* meb2 = (const float*)d_in[5];
  const float* qw   = (const float*)d_in[6];
  const float* qb   = (const float*)d_in[7];
  const float* kvw  = (const float*)d_in[8];
  const float* kvb  = (const float*)d_in[9];
  const float* qnw  = (const float*)d_in[10];
  const float* knw  = (const float*)d_in[11];
  const float* ow   = (const float*)d_in[12];
  const float* ob   = (const float*)d_in[13];

  char* ws = (char*)d_ws;
  float*    emb    = (float*)(ws + 0);          // 16x512 f32
  float*    kvpart = (float*)(ws + 32768);      // 16x6144 f32
  float*    kn     = (float*)(ws + 425984);     // 3x1024 f32
  float*    vv     = (float*)(ws + 438272);     // 3x1024 f32
  ushort_t* qwt    = (ushort_t*)(ws + 450560);  // [1024][3072] bf16
  float*    U      = (float*)(ws + 6742016);    // [48][3072] f32
  float*    base   = (float*)(ws + 7331840);    // [3072] f32
  ushort_t* Dt     = (ushort_t*)(ws + 7344128); // [3072][32] bf16
  u32*      acoefb = (u32*)(ws + 7540736);      // [10560][16] u32 (2xbf16)
  float*    h1buf  = (float*)(ws + 8216576);    // 16x512 f32

  // xb (bf16 x) lives in d_out: needed only until the Q-GEMM; k_rankmm
  // fully overwrites d_out at the end of every call.
  ushort_t* xb = (ushort_t*)d_out;

  k_pre1<<<8, 256, 0, stream>>>(cond, mew1, meb1, h1buf);
  k_pre2<<<32, 256, 0, stream>>>(h1buf, mew2, meb2, emb);
  k_kv<<<384, 256, 0, stream>>>(emb, kvw, kvpart);
  k_knorm<<<1, 256, 0, stream>>>(kvpart, kvb, knw, kn, vv);
  k_uv<<<288, 512, 0, stream>>>(vv, ow, U);
  k_ubase<<<12, 256, 0, stream>>>(U, ob, base, Dt);
  k_tconv<<<3072, 256, 0, stream>>>(qw, qwt, 3072, 1024);
  k_xconv<<<2048, 256, 0, stream>>>(x, xb, (TOK * CIMG) / 4);
  gemm_fused<<<440, 512, 0, stream>>>(xb, qwt, qb, kn, qnw, acoefb);
  k_rankmm<<<990, 256, 0, stream>>>(x, (const ushort_t*)acoefb, Dt, base, (float*)d_out);
}

// Round 13
// 292.066 us; speedup vs baseline: 1.1458x; 1.0525x over previous
//
#include <hip/hip_runtime.h>

#define TOK  10560
#define CIMG 3072
#define KHD  1024

typedef unsigned short ushort_t;
typedef unsigned int u32;
using bf16x8 = __attribute__((ext_vector_type(8))) __bf16;
using f32x4  = __attribute__((ext_vector_type(4))) float;

#define GLD_LDS16(gp, lp) __builtin_amdgcn_global_load_lds( \
    (const __attribute__((address_space(1))) u32*)(gp), \
    (__attribute__((address_space(3))) u32*)(lp), 16, 0, 0)

static __device__ __forceinline__ unsigned short f2bf(float f){
  union { float f; unsigned u; } x; x.f = f;
  unsigned r = x.u + 0x7fffu + ((x.u >> 16) & 1u);
  return (unsigned short)(r >> 16);
}
static __device__ __forceinline__ float wave_sum(float v){
  #pragma unroll
  for (int off = 32; off > 0; off >>= 1) v += __shfl_xor(v, off, 64);
  return v;
}

// ---------------- conditioning MLP layer 1: h1 = silu(cp@w1+b1) --------------
__global__ __launch_bounds__(256) void k_pre1(const float* __restrict__ cond,
    const float* __restrict__ w1, const float* __restrict__ b1,
    float* __restrict__ h1){
  __shared__ float cs[16][16];
  int t = threadIdx.x;
  if (t < 256) cs[t >> 4][t & 15] = cond[(64 + (t >> 4)) * 16 + (t & 15)];
  __syncthreads();
  #pragma unroll
  for (int i = 0; i < 4; ++i){
    int idx = blockIdx.x * 256 + t + i * 2048;
    int r = idx >> 9, c = idx & 511;
    float s = b1[c];
    #pragma unroll
    for (int j = 0; j < 16; ++j) s += cs[r][j] * w1[j * 512 + c];
    h1[idx] = s / (1.f + __expf(-s));   // silu
  }
}

// ---------------- conditioning MLP layer 2: emb = h1@w2 + b2 -----------------
__global__ __launch_bounds__(256) void k_pre2(const float* __restrict__ h1,
    const float* __restrict__ w2, const float* __restrict__ b2,
    float* __restrict__ emb){
  int idx = blockIdx.x * 256 + threadIdx.x;
  int r = idx >> 9, c = idx & 511;
  const float* hp = h1 + r * 512;
  const float* wp = w2 + c;
  float acc = b2[c];
  #pragma unroll 8
  for (int j = 0; j < 512; ++j) acc += hp[j] * wp[(size_t)j * 512];
  emb[idx] = acc;
}

// ---------------- kv = mf @ kv_w, split-K partials (deterministic) ----------
__global__ __launch_bounds__(256) void k_kv(const float* __restrict__ emb,
                                            const float* __restrict__ kvw,
                                            float* __restrict__ part){
  int bl = blockIdx.x;                 // 3 l * 8 ntile * 16 kchunk = 384
  int l = bl / 128, rem = bl % 128, nt = rem / 16, kc = rem % 16;
  int n = nt * 256 + threadIdx.x;
  const float* e = emb + 2048 * l + kc * 256;   // mf[l][r] = emb[2048l + r]
  const float* w = kvw + (size_t)(kc * 256) * 2048 + n;
  float acc = 0.f;
  for (int r = 0; r < 256; ++r) acc += e[r] * w[(size_t)r * 2048];
  part[kc * 6144 + l * 2048 + n] = acc;
}

// ---------------- reduce partials, bias, k-RMSNorm ---------------------------
__global__ void k_knorm(const float* __restrict__ part, const float* __restrict__ kvb,
                        const float* __restrict__ knw, float* __restrict__ kn,
                        float* __restrict__ vv){
  int wid = threadIdx.x >> 6, lane = threadIdx.x & 63;
  for (int i = 0; i < 12; ++i){
    int g = wid * 12 + i;               // 0..47 = (l,h)
    int l = g >> 4, h = g & 15;
    int ik = l * 2048 + h * 64 + lane;
    float kk = kvb[h * 64 + lane];
    float v  = kvb[1024 + h * 64 + lane];
    for (int p = 0; p < 16; ++p){ kk += part[p * 6144 + ik]; v += part[p * 6144 + ik + 1024]; }
    float ss = wave_sum(kk * kk);
    kn[l * 1024 + h * 64 + lane] = kk * rsqrtf(ss * (1.f/64.f) + 1e-6f) * knw[lane];
    vv[l * 1024 + h * 64 + lane] = v;
  }
}

// ---------------- transpose + f32->bf16 weight convert: dst[C][R] ------------
__global__ __launch_bounds__(256) void k_tconv(const float* __restrict__ src,
                                               ushort_t* __restrict__ dst,
                                               int R, int C){
  __shared__ float tile[32][33];
  int nTr = R >> 5;
  int tr = blockIdx.x % nTr, tc = blockIdx.x / nTr;
  int r0 = tr * 32, c0 = tc * 32, t = threadIdx.x;
  #pragma unroll
  for (int i = 0; i < 4; ++i){
    int idx = t + i * 256; int r = idx >> 5, c = idx & 31;
    tile[r][c] = src[(size_t)(r0 + r) * C + c0 + c];
  }
  __syncthreads();
  #pragma unroll
  for (int i = 0; i < 4; ++i){
    int idx = t + i * 256; int rr = idx >> 5, cc = idx & 31;
    dst[(size_t)(c0 + rr) * R + r0 + cc] = f2bf(tile[cc][rr]);
  }
}

// ---------------- x f32 -> bf16 streaming convert ----------------------------
__global__ __launch_bounds__(256) void k_xconv(const float* __restrict__ x,
                                               ushort_t* __restrict__ xb, int n4){
  for (int i = blockIdx.x * 256 + threadIdx.x; i < n4; i += gridDim.x * 256){
    float4 v = ((const float4*)x)[i];
    ushort4 o;
    o.x = f2bf(v.x); o.y = f2bf(v.y); o.z = f2bf(v.z); o.w = f2bf(v.w);
    ((ushort4*)xb)[i] = o;
  }
}

// ======== 192x128 bf16 MFMA Q-GEMM, 2 blocks/CU, fused attn (r12, 120us) =====
__global__ __launch_bounds__(512, 4) void gemm_fused(
    const ushort_t* __restrict__ A, const ushort_t* __restrict__ Bt,
    const float* __restrict__ bias, const float* __restrict__ kn,
    const float* __restrict__ qnw, float* __restrict__ acoef){
  __shared__ __align__(16) unsigned char lds[81920]; // 2 buf x (A 24K + B 16K)
  const int tid = threadIdx.x;
  const int lane = tid & 63, wid = tid >> 6;
  const int wm = wid >> 1, wn = wid & 1;     // 4 x 2 waves -> per-wave 48x64
  const int l15 = lane & 15, kg = lane >> 4;

  // XCD swizzle: 440 = 8 * 55 -> bijective
  int bid = blockIdx.x;
  bid = (bid & 7) * 55 + (bid >> 3);
  const int mt = bid >> 3, nt = bid & 7;
  const int mbase = mt * 192, nbase = nt << 7;

  const int sr  = tid >> 1;                       // 0..191 (tid<384)
  const int skh = (tid & 1) ^ ((sr >> 2) & 1);    // inverse swizzle on source
  const ushort_t* gA = A + (size_t)(mbase + sr) * CIMG + skh * 8;
  const int u   = tid - 384;                      // 0..127
  const int skb = (u & 1) ^ ((u >> 3) & 1);
  const ushort_t* gB0 = Bt + (size_t)(nbase + (u >> 1)) * CIMG + skb * 8;
  const ushort_t* gB1 = gB0 + (size_t)64 * CIMG;

  auto stage = [&](int t, int c, int b){
    const int gk = t * 64 + c * 16;
    if (wid < 6){
      unsigned char* dst = lds + b * 40960 + c * 6144 + wid * 1024;
      GLD_LDS16(gA + gk, dst);
    } else {
      unsigned char* dst = lds + b * 40960 + 24576 + c * 4096 + (wid - 6) * 1024;
      GLD_LDS16(gB0 + gk, dst);
      GLD_LDS16(gB1 + gk, dst + 2048);
    }
  };
#define WAITC2 { if (wid < 6) asm volatile("s_waitcnt vmcnt(2)" ::: "memory"); \
                 else         asm volatile("s_waitcnt vmcnt(4)" ::: "memory"); }

  const int arl = wm * 48 + l15;
  const int brl = wn * 64 + l15;
  const int kh  = ((kg & 1) ^ ((l15 >> 2) & 1)) * 16;
  const unsigned aBase = (unsigned)((kg >> 1) * 6144 + arl * 32 + kh);
  const unsigned bBase = (unsigned)(24576 + (kg >> 1) * 4096 + brl * 32 + kh);

  f32x4 acc[3][4];
  #pragma unroll
  for (int m = 0; m < 3; ++m)
    #pragma unroll
    for (int n = 0; n < 4; ++n) acc[m][n] = {0.f, 0.f, 0.f, 0.f};

  bf16x8 afr[3], bfr[4];

#define PH_READ(base, KSL) { _Pragma("unroll") \
    for (int n = 0; n < 4; ++n) \
      bfr[n] = *(const bf16x8*)((base) + bBase + (KSL)*8192 + n*512); \
    _Pragma("unroll") \
    for (int m = 0; m < 3; ++m) \
      afr[m] = *(const bf16x8*)((base) + aBase + (KSL)*12288 + m*512); }
#define PH_MFMA { __builtin_amdgcn_s_setprio(1); _Pragma("unroll") \
    for (int m = 0; m < 3; ++m){ _Pragma("unroll") \
      for (int n = 0; n < 4; ++n) \
        acc[m][n] = __builtin_amdgcn_mfma_f32_16x16x32_bf16(afr[m], bfr[n], acc[m][n], 0, 0, 0); } \
    __builtin_amdgcn_s_setprio(0); }

  const int T = CIMG / 64;   // 48

  stage(0, 0, 0); stage(0, 1, 0); stage(0, 2, 0); stage(0, 3, 0);
  WAITC2;
  __builtin_amdgcn_s_barrier();

  for (int t = 0; t < T - 1; ++t){
    const int b = t & 1;
    const unsigned char* base = lds + b * 40960;
    PH_READ(base, 0);
    stage(t + 1, 0, b ^ 1); stage(t + 1, 1, b ^ 1);
    WAITC2;
    __builtin_amdgcn_s_barrier();
    PH_MFMA;
    __builtin_amdgcn_s_barrier();
    PH_READ(base, 1);
    stage(t + 1, 2, b ^ 1); stage(t + 1, 3, b ^ 1);
    WAITC2;
    __builtin_amdgcn_s_barrier();
    PH_MFMA;
    __builtin_amdgcn_s_barrier();
  }
  {
    const unsigned char* base = lds + ((T - 1) & 1) * 40960;
    PH_READ(base, 0);
    asm volatile("s_waitcnt vmcnt(0)" ::: "memory");
    __builtin_amdgcn_s_barrier();
    PH_MFMA;
    __builtin_amdgcn_s_barrier();
    PH_READ(base, 1);
    PH_MFMA;
  }
#undef PH_READ
#undef PH_MFMA
#undef WAITC2

  // -------- fused attention epilogue (registers + 16-lane shfl only) --------
  const int hglob = nt * 2 + wn;            // global head, 0..15
  float qnwv[4], qbv[4], knv0[4], knv1[4], knv2[4];
  #pragma unroll
  for (int n = 0; n < 4; ++n){
    int d = n * 16 + l15;
    qnwv[n] = qnw[d];
    qbv[n]  = bias[nbase + wn * 64 + d];
    knv0[n] = kn[hglob * 64 + d];
    knv1[n] = kn[1024 + hglob * 64 + d];
    knv2[n] = kn[2048 + hglob * 64 + d];
  }
  #pragma unroll
  for (int m = 0; m < 3; ++m){
    #pragma unroll
    for (int j = 0; j < 4; ++j){
      float q[4], ssq = 0.f;
      #pragma unroll
      for (int n = 0; n < 4; ++n){ q[n] = acc[m][n][j] + qbv[n]; ssq += q[n] * q[n]; }
      #pragma unroll
      for (int off = 1; off < 16; off <<= 1) ssq += __shfl_xor(ssq, off, 64);
      float rs = rsqrtf(ssq * (1.f/64.f) + 1e-6f);
      float s0 = 0.f, s1 = 0.f, s2 = 0.f;
      #pragma unroll
      for (int n = 0; n < 4; ++n){
        float qn = q[n] * rs * qnwv[n];
        s0 += qn * knv0[n]; s1 += qn * knv1[n]; s2 += qn * knv2[n];
      }
      #pragma unroll
      for (int off = 1; off < 16; off <<= 1){
        s0 += __shfl_xor(s0, off, 64);
        s1 += __shfl_xor(s1, off, 64);
        s2 += __shfl_xor(s2, off, 64);
      }
      s0 *= 0.125f; s1 *= 0.125f; s2 *= 0.125f;
      float mx = fmaxf(s0, fmaxf(s1, s2));
      float e0 = __expf(s0 - mx), e1 = __expf(s1 - mx), e2 = __expf(s2 - mx);
      float inv = 1.f / (e0 + e1 + e2);
      int grow = mbase + wm * 48 + m * 16 + kg * 4 + j;
      if (l15 == 0){
        float2 a12 = {e1 * inv, e2 * inv};
        *(float2*)(acoef + (size_t)grow * 32 + hglob * 2) = a12;
      }
    }
  }
}

// ------- U[h*3+l][c] = sum_d v[l,h,d] * out_w[h*64+d][c]  (48 x 3072, f32) ---
__global__ __launch_bounds__(512) void k_uv(const float* __restrict__ vv,
    const float* __restrict__ ow, float* __restrict__ U){
  int b = blockIdx.x;             // 48 i * 6 cchunk = 288
  int i = b / 6, cc = b % 6;
  int h = i / 3, l = i % 3;
  int c = cc * 512 + threadIdx.x;
  const float* vp = vv + l * 1024 + h * 64;
  const float* wp = ow + (size_t)(h * 64) * 3072 + c;
  float acc = 0.f;
  #pragma unroll
  for (int d = 0; d < 64; ++d) acc += vp[d] * wp[(size_t)d * 3072];
  U[(size_t)i * 3072 + c] = acc;
}

// ------- base[c] = ob[c] + sum_h U[h*3][c];  D[h*2+l'][c] = U[h*3+1+l']-U[h*3]
__global__ __launch_bounds__(256) void k_ubase(const float* __restrict__ U,
    const float* __restrict__ ob, float* __restrict__ base, float* __restrict__ D){
  int c = blockIdx.x * 256 + threadIdx.x;   // 12 blocks
  float b = ob[c];
  #pragma unroll
  for (int h = 0; h < 16; ++h){
    float u0 = U[(size_t)(h * 3 + 0) * 3072 + c];
    float u1 = U[(size_t)(h * 3 + 1) * 3072 + c];
    float u2 = U[(size_t)(h * 3 + 2) * 3072 + c];
    b += u0;
    D[(size_t)(h * 2 + 0) * 3072 + c] = u1 - u0;
    D[(size_t)(h * 2 + 1) * 3072 + c] = u2 - u0;
  }
  base[c] = b;
}

// ------- out = x + base + acoef @ D  (rank-32, float4 I/O) -------------------
// Thread = 4 consecutive cols x 8 rows; block = 8 rows x 1024 cols.
// Grid 1320 rtiles * 3 cchunks = 3960 blocks. a-tile 1KB LDS (broadcast reads);
// D rows are L2-resident (393KB), amortized over 8 rows. x/out: float4 streams.
__global__ __launch_bounds__(256) void k_rank32v(const float* __restrict__ x,
    const float* __restrict__ acoef, const float* __restrict__ D,
    const float* __restrict__ base, float* __restrict__ out){
  __shared__ __align__(16) float as[8][32];
  const int tid = threadIdx.x;
  const int rb = blockIdx.x / 3, cc = blockIdx.x % 3;
  const int r0 = rb * 8;                     // 1320*8 = 10560 exact
  const int c  = cc * 1024 + tid * 4;

  if (tid < 256) ((float*)as)[tid] = acoef[(size_t)r0 * 32 + tid];
  __syncthreads();

  f32x4 accv[8];
  #pragma unroll
  for (int r = 0; r < 8; ++r) accv[r] = {0.f, 0.f, 0.f, 0.f};

  #pragma unroll 4
  for (int k = 0; k < 32; ++k){
    f32x4 d4 = *(const f32x4*)(D + (size_t)k * 3072 + c);
    #pragma unroll
    for (int r = 0; r < 8; ++r){
      float a = as[r][k];
      accv[r][0] += a * d4[0]; accv[r][1] += a * d4[1];
      accv[r][2] += a * d4[2]; accv[r][3] += a * d4[3];
    }
  }

  f32x4 b4 = *(const f32x4*)(base + c);
  #pragma unroll
  for (int r = 0; r < 8; ++r){
    const size_t o = (size_t)(r0 + r) * 3072 + c;
    f32x4 xv = *(const f32x4*)(x + o);
    f32x4 ov;
    ov[0] = xv[0] + b4[0] + accv[r][0];
    ov[1] = xv[1] + b4[1] + accv[r][1];
    ov[2] = xv[2] + b4[2] + accv[r][2];
    ov[3] = xv[3] + b4[3] + accv[r][3];
    *(f32x4*)(out + o) = ov;
  }
}

extern "C" void kernel_launch(void* const* d_in, const int* in_sizes, int n_in,
                              void* d_out, int out_size, void* d_ws, size_t ws_size,
                              hipStream_t stream){
  const float* x    = (const float*)d_in[0];
  const float* cond = (const float*)d_in[1];
  const float* mew1 = (const float*)d_in[2];
  const float* meb1 = (const float*)d_in[3];
  const float* mew2 = (const float*)d_in[4];
  const float* meb2 = (const float*)d_in[5];
  const float* qw   = (const float*)d_in[6];
  const float* qb   = (const float*)d_in[7];
  const float* kvw  = (const float*)d_in[8];
  const float* kvb  = (const float*)d_in[9];
  const float* qnw  = (const float*)d_in[10];
  const float* knw  = (const float*)d_in[11];
  const float* ow   = (const float*)d_in[12];
  const float* ob   = (const float*)d_in[13];

  char* ws = (char*)d_ws;
  float*    emb    = (float*)(ws + 0);          // 16x512 f32
  float*    kvpart = (float*)(ws + 32768);      // 16x6144 f32
  float*    kn     = (float*)(ws + 425984);     // 3x1024 f32
  float*    vv     = (float*)(ws + 438272);     // 3x1024 f32
  ushort_t* qwt    = (ushort_t*)(ws + 450560);  // [1024][3072] bf16
  float*    U      = (float*)(ws + 6742016);    // [48][3072] f32
  float*    base   = (float*)(ws + 7331840);    // [3072] f32
  float*    Dbuf   = (float*)(ws + 7344128);    // [32][3072] f32
  float*    acoef  = (float*)(ws + 7737344);    // [10560][32] f32
  float*    h1buf  = (float*)(ws + 9089024);    // 16x512 f32

  // xb (bf16 x) lives in d_out: needed only until the Q-GEMM; k_rank32v
  // fully overwrites d_out at the end of every call.
  ushort_t* xb = (ushort_t*)d_out;

  k_pre1<<<8, 256, 0, stream>>>(cond, mew1, meb1, h1buf);
  k_pre2<<<32, 256, 0, stream>>>(h1buf, mew2, meb2, emb);
  k_kv<<<384, 256, 0, stream>>>(emb, kvw, kvpart);
  k_knorm<<<1, 256, 0, stream>>>(kvpart, kvb, knw, kn, vv);
  k_uv<<<288, 512, 0, stream>>>(vv, ow, U);
  k_ubase<<<12, 256, 0, stream>>>(U, ob, base, Dbuf);
  k_tconv<<<3072, 256, 0, stream>>>(qw, qwt, 3072, 1024);
  k_xconv<<<2048, 256, 0, stream>>>(x, xb, (TOK * CIMG) / 4);
  gemm_fused<<<440, 512, 0, stream>>>(xb, qwt, qb, kn, qnw, acoef);
  k_rank32v<<<3960, 256, 0, stream>>>(x, acoef, Dbuf, base, (float*)d_out);
}